// Round 10
// baseline (2815.396 us; speedup 1.0000x reference)
//
#include <hip/hip_runtime.h>
#include <math.h>

#define NB 8
#define NN 2048
#define NM 2048
#define NITERS 50

static constexpr float LOG2E  = 1.4426950408889634f;
static constexpr float KK     = LOG2E / 0.005f;     // 288.539...
static constexpr float TWOK   = 2.0f * KK;
static constexpr float NEG_LOG2N = -11.0f;          // -log2(2048)

__device__ __forceinline__ float fexp2(float x) { return __builtin_amdgcn_exp2f(x); }
__device__ __forceinline__ float flog2(float x) { return __builtin_amdgcn_logf(x); }

// sc1 (agent-coherent, L3-direct) accesses via relaxed atomics — R9-proven.
__device__ __forceinline__ float ld_sc1(const float* p) {
    return __hip_atomic_load(p, __ATOMIC_RELAXED, __HIP_MEMORY_SCOPE_AGENT);
}
__device__ __forceinline__ void st_sc1(float* p, float v) {
    __hip_atomic_store(p, v, __ATOMIC_RELAXED, __HIP_MEMORY_SCOPE_AGENT);
}
__device__ __forceinline__ int ld_flag(const int* p) {
    return __hip_atomic_load(p, __ATOMIC_RELAXED, __HIP_MEMORY_SCOPE_AGENT);
}
__device__ __forceinline__ void st_flag(int* p, int v) {
    __hip_atomic_store(p, v, __ATOMIC_RELAXED, __HIP_MEMORY_SCOPE_AGENT);
}

// Wait until the 8 producer-block flags of group g reach `target`.
// 64 lanes poll 8 words (lane&7) -> __all ballot. Monotone ints, no RMW.
__device__ __forceinline__ void wait_group(const int* __restrict__ fl, int g,
                                           int target, int lane)
{
    const int* p = fl + g * 8 + (lane & 7);
    for (;;) {
        const int v = ld_flag(p);
        if (__all(v >= target)) break;
        __builtin_amdgcn_s_sleep(2);
    }
}

// ---------------------------------------------------------------------------
// One half-sweep LSE for this thread's row over all 2048 m (m = 16k + ms).
// Depth-2 rotate: compute group g on d[] (loaded in iter g-1) while the flag
// probe for g+2 is in flight; D loads issue only after flags observed.
// z' = D_m + fmaf(xs0,Q.x, fmaf(xs1,Q.y, fmaf(xs2,Q.z, Q.w)))  [K|row|^2 folded out]
// Chunk-4 streaming LSE + 16-lane shfl_xor fold (order-independent merge).
// ---------------------------------------------------------------------------
__device__ __forceinline__ float sweep_lse(
    const float*  __restrict__ Din,   // opposite duals (sc1), + b*N
    const float4* __restrict__ Qin,   // opposite packed statics (cached), + b*N
    const int*    __restrict__ fl,    // opposite flags, + b*128
    int target, float xs0, float xs1, float xs2, int ms, int lane)
{
    float rm = -1e30f, rs = 0.f;
    float d[8], dn[8];

    wait_group(fl, 0, target, lane);
    wait_group(fl, 1, target, lane);
    #pragma unroll
    for (int j = 0; j < 8; ++j) d[j]  = ld_sc1(Din + 0 * 128 + j * 16 + ms);
    #pragma unroll
    for (int j = 0; j < 8; ++j) dn[j] = ld_sc1(Din + 1 * 128 + j * 16 + ms);
    int pv = ld_flag(fl + 2 * 8 + (lane & 7));   // probe group 2 (evaluated later)

    #pragma unroll 1
    for (int g = 0; g < 16; ++g) {
        const float4* __restrict__ qb = Qin + g * 128 + ms;
        #pragma unroll
        for (int c = 0; c < 2; ++c) {
            const float4 q0 = qb[(4 * c + 0) * 16];
            const float4 q1 = qb[(4 * c + 1) * 16];
            const float4 q2 = qb[(4 * c + 2) * 16];
            const float4 q3 = qb[(4 * c + 3) * 16];
            const float z0 = d[4*c+0] + fmaf(xs0, q0.x, fmaf(xs1, q0.y, fmaf(xs2, q0.z, q0.w)));
            const float z1 = d[4*c+1] + fmaf(xs0, q1.x, fmaf(xs1, q1.y, fmaf(xs2, q1.z, q1.w)));
            const float z2 = d[4*c+2] + fmaf(xs0, q2.x, fmaf(xs1, q2.y, fmaf(xs2, q2.z, q2.w)));
            const float z3 = d[4*c+3] + fmaf(xs0, q3.x, fmaf(xs1, q3.y, fmaf(xs2, q3.z, q3.w)));
            const float cm = fmaxf(fmaxf(z0, z1), fmaxf(z2, z3));
            const float nm = fmaxf(rm, cm);
            const float s  = (fexp2(z0 - nm) + fexp2(z1 - nm))
                           + (fexp2(z2 - nm) + fexp2(z3 - nm));
            rs = fmaf(rs, fexp2(rm - nm), s);
            rm = nm;
        }
        if (g < 14) {
            if (!__all(pv >= target)) wait_group(fl, g + 2, target, lane);
            #pragma unroll
            for (int j = 0; j < 8; ++j) d[j] = dn[j];
            #pragma unroll
            for (int j = 0; j < 8; ++j) dn[j] = ld_sc1(Din + (g + 2) * 128 + j * 16 + ms);
            if (g < 13) pv = ld_flag(fl + (g + 3) * 8 + (lane & 7));
        } else if (g == 14) {
            #pragma unroll
            for (int j = 0; j < 8; ++j) d[j] = dn[j];
        }
    }

    // fold the 16 ms-partials of this row (lanes r*16 .. r*16+15)
    #pragma unroll
    for (int w = 1; w <= 8; w <<= 1) {
        const float om = __shfl_xor(rm, w);
        const float os = __shfl_xor(rs, w);
        const float nm = fmaxf(rm, om);
        rs = fmaf(rs, fexp2(rm - nm), os * fexp2(om - nm));
        rm = nm;
    }
    return rm + flog2(rs);     // lse2 of z' (all 16 lanes hold it)
}

// ---------------------------------------------------------------------------
// Persistent dataflow kernel: init -> 50x (f-half, g-half) -> final loss.
// grid = 1024 WGs x 256 thr = 4 WG/CU co-resident (R9-proven geometry,
// LDS now 16 B). No global barrier: per-producer-block flags, in-order
// pipelined consumption. Thread = (row = tid>>4, ms = tid&15).
// ---------------------------------------------------------------------------
__global__ __launch_bounds__(256, 4) void sinkhorn_df(
    const float* __restrict__ X, const float* __restrict__ Y,
    float4* __restrict__ Qx, float4* __restrict__ Qy,
    float* __restrict__ Dx, float* __restrict__ Dy,
    int* __restrict__ Fx, int* __restrict__ Fy,
    float* __restrict__ out)
{
    __shared__ float wsum[4];
    const int tid  = threadIdx.x;
    const int lane = tid & 63;
    const int ms   = tid & 15;
    const int row  = tid >> 4;           // 0..15
    const int b    = blockIdx.x & 7;
    const int wgb  = blockIdx.x >> 3;    // 0..127 within batch
    const int myrow = wgb * 16 + row;

    const float* xp = X + (size_t)(b * NN + myrow) * 3;
    const float* yp = Y + (size_t)(b * NM + myrow) * 3;
    const float x0 = xp[0], x1 = xp[1], x2 = xp[2];
    const float y0 = yp[0], y1 = yp[1], y2 = yp[2];
    const float xsq = fmaf(x0, x0, fmaf(x1, x1, x2 * x2));
    const float ysq = fmaf(y0, y0, fmaf(y1, y1, y2 * y2));
    const float qxw = -KK * xsq, qyw = -KK * ysq;
    const float xs0 = TWOK * x0, xs1 = TWOK * x1, xs2 = TWOK * x2;
    const float ys0 = TWOK * y0, ys1 = TWOK * y1, ys2 = TWOK * y2;

    float4* QxB = Qx + b * NN;  float4* QyB = Qy + b * NM;
    float*  DxB = Dx + b * NN;  float*  DyB = Dy + b * NM;
    int* fxB = Fx + b * 128;    int* fyB = Fy + b * 128;

    // ---- init my 16 rows: statics (sc1) + Dy = 0; then publish both flags.
    if (ms == 0) {
        float4* q = QxB + myrow;
        st_sc1(&q->x, x0); st_sc1(&q->y, x1); st_sc1(&q->z, x2); st_sc1(&q->w, qxw);
    } else if (ms == 1) {
        float4* q = QyB + myrow;
        st_sc1(&q->x, y0); st_sc1(&q->y, y1); st_sc1(&q->z, y2); st_sc1(&q->w, qyw);
    } else if (ms == 2) {
        st_sc1(DyB + myrow, 0.f);
    }
    asm volatile("s_waitcnt vmcnt(0)" ::: "memory");
    __syncthreads();
    if (tid == 0) { st_flag(fxB + wgb, 1); st_flag(fyB + wgb, 1); }

    float Af = 0.f;   // K(f - |x|^2) of my row, kept for final loss

    #pragma unroll 1
    for (int it = 0; it < NITERS; ++it) {
        // f-update: consume Dy/Qy (need fy >= it+1), publish Dx, fx = it+2
        float lse2 = sweep_lse(DyB, QyB, fyB, it + 1, xs0, xs1, xs2, ms, lane);
        const float fd = NEG_LOG2N - lse2 - qxw;   // K * f
        Af = NEG_LOG2N - lse2;                      // fd + qxw
        if (ms == 0) st_sc1(DxB + myrow, fd);
        asm volatile("s_waitcnt vmcnt(0)" ::: "memory");
        __syncthreads();
        if (tid == 0) st_flag(fxB + wgb, it + 2);

        // g-update: consume Dx/Qx (need fx >= it+2), publish Dy, fy = it+2
        lse2 = sweep_lse(DxB, QxB, fxB, it + 2, ys0, ys1, ys2, ms, lane);
        const float gd = NEG_LOG2N - lse2 - qyw;   // K * g
        if (ms == 0) st_sc1(DyB + myrow, gd);
        asm volatile("s_waitcnt vmcnt(0)" ::: "memory");
        __syncthreads();
        if (tid == 0) st_flag(fyB + wgb, it + 2);
    }

    // ---- final loss: own Af in regs; y side gated on fy >= NITERS+1
    {
        const int target = NITERS + 1;
        float acc = 0.f;
        #pragma unroll 1
        for (int g = 0; g < 16; ++g) {
            wait_group(fyB, g, target, lane);
            const float4* __restrict__ qb = QyB + g * 128 + ms;
            const float*  __restrict__ db = DyB + g * 128 + ms;
            #pragma unroll
            for (int j = 0; j < 8; ++j) {
                const float4 q  = qb[j * 16];
                const float  dg = ld_sc1(db + j * 16);
                const float chain = fmaf(xs0, q.x, fmaf(xs1, q.y, fmaf(xs2, q.z, q.w)));
                const float zp  = Af + dg + chain;                 // log2 P
                const float dot = fmaf(x0, q.x, fmaf(x1, q.y, x2 * q.z));
                const float yq  = fmaf(q.x, q.x, fmaf(q.y, q.y, q.z * q.z));
                const float cc  = fmaxf(fmaf(-2.f, dot, xsq + yq), 0.f);
                acc = fmaf(fexp2(zp), cc, acc);
            }
        }
        #pragma unroll
        for (int w = 1; w <= 32; w <<= 1) acc += __shfl_xor(acc, w);
        if (lane == 0) wsum[tid >> 6] = acc;
        __syncthreads();
        if (tid == 0)
            atomicAdd(out, (wsum[0] + wsum[1] + wsum[2] + wsum[3]) * (1.0f / NB));
    }
}

// ---------------------------------------------------------------------------
extern "C" void kernel_launch(void* const* d_in, const int* in_sizes, int n_in,
                              void* d_out, int out_size, void* d_ws, size_t ws_size,
                              hipStream_t stream)
{
    const float* x = (const float*)d_in[0];
    const float* y = (const float*)d_in[1];
    float4* Qx = (float4*)d_ws;                 // [B][N] static packed x
    float4* Qy = Qx + NB * NN;                  // [B][M] static packed y
    float*  Dx = (float*)(Qy + NB * NM);        // [B][N] dynamic K*f
    float*  Dy = Dx + NB * NN;                  // [B][M] dynamic K*g
    int*    Fx = (int*)(Dy + NB * NM);          // [B][128] x-side block flags
    int*    Fy = Fx + NB * 128;                 // [B][128] y-side block flags

    hipMemsetAsync(Fx, 0, 2 * NB * 128 * sizeof(int), stream);
    hipMemsetAsync(d_out, 0, sizeof(float), stream);

    sinkhorn_df<<<NB * NN / 16, 256, 0, stream>>>(x, y, Qx, Qy, Dx, Dy, Fx, Fy,
                                                  (float*)d_out);
}

// Round 11
// 2405.736 us; speedup vs baseline: 1.1703x; 1.1703x over previous
//
#include <hip/hip_runtime.h>
#include <math.h>

#define NB 8
#define NN 2048
#define NM 2048
#define NITERS 50

static constexpr float LOG2E  = 1.4426950408889634f;
static constexpr float KK     = LOG2E / 0.005f;     // 288.539...
static constexpr float TWOK   = 2.0f * KK;
static constexpr float NEG_LOG2N = -11.0f;          // -log2(2048)
static constexpr float SKIP   = 28.0f;              // LSE cutoff: 2^-28 relative
static constexpr float ZP_CUT = -40.0f;             // final-loss cutoff (zp max ~ -11)

typedef float v2f __attribute__((ext_vector_type(2)));

__device__ __forceinline__ float fexp2(float x) { return __builtin_amdgcn_exp2f(x); }
__device__ __forceinline__ float flog2(float x) { return __builtin_amdgcn_logf(x); }
__device__ __forceinline__ v2f fma2(float s, v2f a, v2f b) {
    return __builtin_elementwise_fma((v2f){s, s}, a, b);
}
__device__ __forceinline__ v2f vfma2(v2f a, v2f b, v2f c) {
    return __builtin_elementwise_fma(a, b, c);
}
__device__ __forceinline__ v2f max2(v2f a, v2f b) { return __builtin_elementwise_max(a, b); }

// ---------------------------------------------------------------------------
// SoA pack: Xx/Xy/Xz coords; SwY = -K|y|^2 (A_g with g=0). N == M.
// ---------------------------------------------------------------------------
__global__ void pack_soa(const float* __restrict__ X, const float* __restrict__ Y,
                         float* __restrict__ Xx, float* __restrict__ Xy, float* __restrict__ Xz,
                         float* __restrict__ Yx, float* __restrict__ Yy, float* __restrict__ Yz,
                         float* __restrict__ SwY)
{
    int i = blockIdx.x * blockDim.x + threadIdx.x;
    if (i < NB * NN) {
        float a = X[3*i], b = X[3*i+1], c = X[3*i+2];
        Xx[i] = a; Xy[i] = b; Xz[i] = c;
        float d = Y[3*i], e = Y[3*i+1], f = Y[3*i+2];
        Yx[i] = d; Yy[i] = e; Yz[i] = f;
        SwY[i] = -KK * fmaf(d, d, fmaf(e, e, f * f));
    }
}

// ---------------------------------------------------------------------------
// Sinkhorn half-sweep, two-pass exp-elimination LSE.
//   grid = 1024 WGs x 256 thr; b = blockIdx&7 (batch->XCD pinned; a CU's 4
//   WGs share one batch -> 32KB L1-resident). WG = 16 rows x all 2048 m.
//   Lane owns 4 consecutive m's per chunk (SoA float4 loads, coalesced);
//   wave = m-quarter; 2 chunks/lane.
//   P1: z-chain (pk_fma) + max only. P2: reload (L1-hot), recompute chain,
//   exp/sum ONLY for chunks with __any(cmax > rm-28) -- at K=288.5 the z
//   spread is huge, so almost all exp work is skipped (error <= 2048*2^-28).
//   Fold of (rm, rs) partials = R8's verified 2-stage LDS combine.
// ---------------------------------------------------------------------------
__global__ __launch_bounds__(256, 4) void sink_update(
    const float* __restrict__ Ux, const float* __restrict__ Uy,
    const float* __restrict__ Uz, const float* __restrict__ Uw,   // opposite side (Uw dynamic)
    const float* __restrict__ Ox, const float* __restrict__ Oy,
    const float* __restrict__ Oz,                                 // own coords
    float* __restrict__ SwOut)                                    // own A-out
{
    __shared__ float2 part [16][257];
    __shared__ float2 part2[16][17];
    const int tid  = threadIdx.x;
    const int lane = tid & 63;
    const int wave = tid >> 6;
    const int b    = blockIdx.x & 7;
    const int wgb  = blockIdx.x >> 3;
    const int rowbase = wgb * 16;

    float xs0[16], xs1[16], xs2[16];
    #pragma unroll
    for (int r = 0; r < 16; ++r) {
        const int n = b * NN + rowbase + r;
        xs0[r] = TWOK * Ox[n]; xs1[r] = TWOK * Oy[n]; xs2[r] = TWOK * Oz[n];
    }

    const int m0 = b * NM + wave * 512 + lane * 4;

    float rm[16];
    #pragma unroll
    for (int r = 0; r < 16; ++r) rm[r] = -1e30f;

    // ---- P1: max only (6 pk_fma + 2 pk_max per 4 m's per row)
    #pragma unroll
    for (int c = 0; c < 2; ++c) {
        const int mo = m0 + c * 256;
        const float4 vx = *(const float4*)(Ux + mo);
        const float4 vy = *(const float4*)(Uy + mo);
        const float4 vz = *(const float4*)(Uz + mo);
        const float4 vw = *(const float4*)(Uw + mo);
        const v2f xlo = {vx.x, vx.y}, xhi = {vx.z, vx.w};
        const v2f ylo = {vy.x, vy.y}, yhi = {vy.z, vy.w};
        const v2f zlo = {vz.x, vz.y}, zhi = {vz.z, vz.w};
        const v2f wlo = {vw.x, vw.y}, whi = {vw.z, vw.w};
        #pragma unroll
        for (int r = 0; r < 16; ++r) {
            v2f za = fma2(xs0[r], xlo, wlo);
            za     = fma2(xs1[r], ylo, za);
            za     = fma2(xs2[r], zlo, za);
            v2f zb = fma2(xs0[r], xhi, whi);
            zb     = fma2(xs1[r], yhi, zb);
            zb     = fma2(xs2[r], zhi, zb);
            const v2f mm = max2(za, zb);
            rm[r] = fmaxf(rm[r], fmaxf(mm.x, mm.y));
        }
    }

    // ---- P2: recompute chain (L1-hot reload), selective exp/sum
    float rs[16];
    #pragma unroll
    for (int r = 0; r < 16; ++r) rs[r] = 0.f;

    #pragma unroll
    for (int c = 0; c < 2; ++c) {
        const int mo = m0 + c * 256;
        const float4 vx = *(const float4*)(Ux + mo);
        const float4 vy = *(const float4*)(Uy + mo);
        const float4 vz = *(const float4*)(Uz + mo);
        const float4 vw = *(const float4*)(Uw + mo);
        const v2f xlo = {vx.x, vx.y}, xhi = {vx.z, vx.w};
        const v2f ylo = {vy.x, vy.y}, yhi = {vy.z, vy.w};
        const v2f zlo = {vz.x, vz.y}, zhi = {vz.z, vz.w};
        const v2f wlo = {vw.x, vw.y}, whi = {vw.z, vw.w};
        #pragma unroll
        for (int r = 0; r < 16; ++r) {
            v2f za = fma2(xs0[r], xlo, wlo);
            za     = fma2(xs1[r], ylo, za);
            za     = fma2(xs2[r], zlo, za);
            v2f zb = fma2(xs0[r], xhi, whi);
            zb     = fma2(xs1[r], yhi, zb);
            zb     = fma2(xs2[r], zhi, zb);
            const v2f mm = max2(za, zb);
            const float cm = fmaxf(mm.x, mm.y);
            if (__any(cm > rm[r] - SKIP)) {          // wave-uniform branch
                const float e0 = fexp2(za.x - rm[r]);
                const float e1 = fexp2(za.y - rm[r]);
                const float e2 = fexp2(zb.x - rm[r]);
                const float e3 = fexp2(zb.y - rm[r]);
                rs[r] += (e0 + e1) + (e2 + e3);
            }
        }
    }

    // ---- fold 256 (rm, rs) partials per row (R8-verified 2-stage combine)
    #pragma unroll
    for (int r = 0; r < 16; ++r) part[r][tid] = make_float2(rm[r], rs[r]);
    __syncthreads();

    {
        const int row = tid & 15, seg = tid >> 4;
        float m16 = -1e30f;
        float2 v[16];
        #pragma unroll
        for (int k = 0; k < 16; ++k) { v[k] = part[row][seg*16 + k]; m16 = fmaxf(m16, v[k].x); }
        float s16 = 0.f;
        #pragma unroll
        for (int k = 0; k < 16; ++k) s16 = fmaf(v[k].y, fexp2(v[k].x - m16), s16);
        part2[row][seg] = make_float2(m16, s16);
    }
    __syncthreads();

    if (tid < 16) {
        float gm = -1e30f;
        float2 v[16];
        #pragma unroll
        for (int k = 0; k < 16; ++k) { v[k] = part2[tid][k]; gm = fmaxf(gm, v[k].x); }
        float s = 0.f;
        #pragma unroll
        for (int k = 0; k < 16; ++k) s = fmaf(v[k].y, fexp2(v[k].x - gm), s);
        const float lse2 = gm + flog2(s);
        SwOut[b * NN + rowbase + tid] = NEG_LOG2N - lse2;   // A = K(dual - |v|^2)
    }
}

// ---------------------------------------------------------------------------
// Final loss with absolute cutoff (zp = log2 P <= -11; skip chunks below -40).
// out = (1/B) * sum exp2(zp) * C,  zp = Af + Ag + 2K*dot,
// C = max(|x|^2+|y|^2-2dot, 0).
// ---------------------------------------------------------------------------
__global__ __launch_bounds__(256, 4) void final_loss(
    const float* __restrict__ Xx, const float* __restrict__ Xy,
    const float* __restrict__ Xz, const float* __restrict__ SwX,
    const float* __restrict__ Yx, const float* __restrict__ Yy,
    const float* __restrict__ Yz, const float* __restrict__ SwY,
    float* __restrict__ out)
{
    __shared__ float wsum[4];
    const int tid  = threadIdx.x;
    const int lane = tid & 63;
    const int wave = tid >> 6;
    const int b    = blockIdx.x & 7;
    const int wgb  = blockIdx.x >> 3;
    const int rowbase = wgb * 16;

    float px[16], py[16], pz[16], Af[16], xq[16];
    #pragma unroll
    for (int r = 0; r < 16; ++r) {
        const int n = b * NN + rowbase + r;
        px[r] = Xx[n]; py[r] = Xy[n]; pz[r] = Xz[n];
        Af[r] = SwX[n];
        xq[r] = fmaf(px[r], px[r], fmaf(py[r], py[r], pz[r] * pz[r]));
    }

    const int m0 = b * NM + wave * 512 + lane * 4;

    float acc = 0.f;
    #pragma unroll
    for (int c = 0; c < 2; ++c) {
        const int mo = m0 + c * 256;
        const float4 vx = *(const float4*)(Yx + mo);
        const float4 vy = *(const float4*)(Yy + mo);
        const float4 vz = *(const float4*)(Yz + mo);
        const float4 vw = *(const float4*)(SwY + mo);
        const v2f xlo = {vx.x, vx.y}, xhi = {vx.z, vx.w};
        const v2f ylo = {vy.x, vy.y}, yhi = {vy.z, vy.w};
        const v2f zlo = {vz.x, vz.y}, zhi = {vz.z, vz.w};
        const v2f wlo = {vw.x, vw.y}, whi = {vw.z, vw.w};
        // |y|^2 per element (row-independent, hoisted)
        const v2f yqlo = vfma2(xlo, xlo, vfma2(ylo, ylo, zlo * zlo));
        const v2f yqhi = vfma2(xhi, xhi, vfma2(yhi, yhi, zhi * zhi));
        #pragma unroll
        for (int r = 0; r < 16; ++r) {
            v2f dlo = fma2(px[r], xlo, fma2(py[r], ylo, (v2f){pz[r], pz[r]} * zlo));
            v2f dhi = fma2(px[r], xhi, fma2(py[r], yhi, (v2f){pz[r], pz[r]} * zhi));
            const v2f afb = {Af[r], Af[r]};
            const v2f zplo = fma2(TWOK, dlo, wlo + afb);
            const v2f zphi = fma2(TWOK, dhi, whi + afb);
            const v2f mm = max2(zplo, zphi);
            if (__any(fmaxf(mm.x, mm.y) > ZP_CUT)) {
                const v2f xqb = {xq[r], xq[r]};
                v2f cclo = fma2(-2.f, dlo, yqlo + xqb);
                v2f cchi = fma2(-2.f, dhi, yqhi + xqb);
                cclo = max2(cclo, (v2f){0.f, 0.f});
                cchi = max2(cchi, (v2f){0.f, 0.f});
                acc = fmaf(fexp2(zplo.x), cclo.x, acc);
                acc = fmaf(fexp2(zplo.y), cclo.y, acc);
                acc = fmaf(fexp2(zphi.x), cchi.x, acc);
                acc = fmaf(fexp2(zphi.y), cchi.y, acc);
            }
        }
    }
    #pragma unroll
    for (int o = 32; o > 0; o >>= 1) acc += __shfl_xor(acc, o);
    if (lane == 0) wsum[wave] = acc;
    __syncthreads();
    if (tid == 0)
        atomicAdd(out, (wsum[0] + wsum[1] + wsum[2] + wsum[3]) * (1.0f / NB));
}

// ---------------------------------------------------------------------------
extern "C" void kernel_launch(void* const* d_in, const int* in_sizes, int n_in,
                              void* d_out, int out_size, void* d_ws, size_t ws_size,
                              hipStream_t stream)
{
    const float* x = (const float*)d_in[0];
    const float* y = (const float*)d_in[1];
    float* w = (float*)d_ws;
    const int NP = NB * NN;
    float* Xx = w;          float* Xy = w + NP;     float* Xz = w + 2*NP;
    float* SwX = w + 3*NP;
    float* Yx = w + 4*NP;   float* Yy = w + 5*NP;   float* Yz = w + 6*NP;
    float* SwY = w + 7*NP;

    pack_soa<<<(NP + 255) / 256, 256, 0, stream>>>(x, y, Xx, Xy, Xz, Yx, Yy, Yz, SwY);

    for (int it = 0; it < NITERS; ++it) {
        sink_update<<<NP / 16, 256, 0, stream>>>(Yx, Yy, Yz, SwY, Xx, Xy, Xz, SwX); // f
        sink_update<<<NP / 16, 256, 0, stream>>>(Xx, Xy, Xz, SwX, Yx, Yy, Yz, SwY); // g
    }

    hipMemsetAsync(d_out, 0, sizeof(float), stream);
    final_loss<<<NP / 16, 256, 0, stream>>>(Xx, Xy, Xz, SwX, Yx, Yy, Yz, SwY, (float*)d_out);
}